// Round 4
// baseline (186.789 us; speedup 1.0000x reference)
//
#include <hip/hip_runtime.h>
#include <hip/hip_bf16.h>

#define C_IN  64
#define C_OUT 128
#define KK    27
#define HH    100000
#define TB    1563         // transpose blocks = ceil(HH/64)
#define WB    108          // weight-convert blocks (108*2048 = 221184 elems)
#define NBLK  782          // ceil(HH/128)

typedef __attribute__((ext_vector_type(8))) short s8v;    // 8 bf16 (MFMA A/B frag)
typedef __attribute__((ext_vector_type(4))) float f32x4;  // MFMA C/D frag

__device__ inline unsigned short f2bf(float f) {
    __hip_bfloat16 h = __float2bfloat16(f);
    return *reinterpret_cast<unsigned short*>(&h);
}

__device__ inline void dma16(const void* g, void* l) {
    __builtin_amdgcn_global_load_lds((const __attribute__((address_space(1))) void*)g,
                                     (__attribute__((address_space(3))) void*)l, 16, 0, 0);
}

// ---- prep: transpose x -> xt (bf16, [h][64] plain), W -> wk (bf16, [k][o][64] XOR-swizzled) ----
// wk physical chunk pj (16B unit) holds logical chunk pj ^ (o&7).
__global__ __launch_bounds__(256) void prep_kernel(const float* __restrict__ x,
                                                   const float* __restrict__ w,
                                                   unsigned short* __restrict__ xt,
                                                   unsigned short* __restrict__ wk) {
    const int tid = threadIdx.x;
    if (blockIdx.x < TB) {
        __shared__ __align__(16) unsigned short ts[64 * 72];
        const int hbase = blockIdx.x * 64;
        #pragma unroll
        for (int it = 0; it < 16; ++it) {
            int i = it * 256 + tid;           // 64h x 64c
            int c = i >> 6, hl = i & 63;
            int hg = hbase + hl;
            float v = (hg < HH) ? x[(size_t)c * HH + hg] : 0.f;  // coalesced in h
            ts[hl * 72 + c] = f2bf(v);
        }
        __syncthreads();
        #pragma unroll
        for (int it = 0; it < 2; ++it) {
            int u = it * 256 + tid;           // 64 rows x 8 chunks of 16B
            int hl = u >> 3, part = u & 7;
            int hg = hbase + hl;
            if (hg < HH)
                *(int4*)&xt[(size_t)hg * 64 + part * 8] = *(const int4*)&ts[hl * 72 + part * 8];
        }
    } else {
        int b = blockIdx.x - TB;
        int base = b * 2048 + tid;
        #pragma unroll
        for (int j = 0; j < 8; ++j) {
            int t = base + j * 256;           // wk index: t = k*8192 + o*64 + jj
            int jj = t & 63, o = (t >> 6) & 127, kx = t >> 13;
            int lc = (jj >> 3) ^ (o & 7);     // logical chunk
            int c  = lc * 8 + (jj & 7);
            wk[t] = f2bf(w[(size_t)o * (C_IN * KK) + c * KK + kx]);
        }
    }
}

// ---------------- main gather-GEMM ----------------
// block 256 thr = 4 waves; tile M=128 (all o) x N=128 h; wave w: h strip [w*32, w*32+32)
// 3 blocks/CU co-resident hide each other's barrier drains.
__global__ __launch_bounds__(256, 3) void conv_main(const unsigned short* __restrict__ xt,
                                                    const unsigned short* __restrict__ wk,
                                                    const int* __restrict__ neigh,
                                                    float* __restrict__ out) {
    __shared__ int neigh_s[128 * KK];                            // 13824 B, [h][k]
    __shared__ __align__(16) unsigned short w_s[2][128 * 64];    // 2 x 16 KB, XOR-swizzled rows

    const int tid  = threadIdx.x;
    const int wave = tid >> 6;
    const int lane = tid & 63;
    const int col  = lane & 15;
    const int quad = lane >> 4;
    const int hbase = blockIdx.x * 128;

    // ---- stage neighbor indices (coalesced) ----
    for (int i = tid; i < 128 * KK; i += 256) {
        int hl = i / KK, kx = i - hl * KK;
        int hg = hbase + hl;
        neigh_s[i] = (hg < HH) ? neigh[(size_t)hg * KK + kx] : -1;
    }

    // ---- W DMA issue helper: 16 KB slice k -> w_s[b] ----
    auto dmaW = [&](int k, int b) {
        const unsigned short* src = wk + (size_t)k * (C_OUT * C_IN);
        #pragma unroll
        for (int i = 0; i < 4; ++i) {
            int row_base = wave * 8 + i * 32;   // 8 rows = 1024 B per inst per wave
            dma16(src + row_base * 64 + lane * 8, &w_s[b][row_base * 64]);
        }
    };

    dmaW(0, 0);

    f32x4 acc[8][2];
    #pragma unroll
    for (int mt = 0; mt < 8; ++mt) {
        acc[mt][0] = (f32x4){0.f, 0.f, 0.f, 0.f};
        acc[mt][1] = (f32x4){0.f, 0.f, 0.f, 0.f};
    }

    __syncthreads();   // neigh_s visible; DMA slice 0 drained

    // ---- B loader: per lane 2 h-cols (nt), 2 chunks each, direct global->VGPR ----
    const int pc_b = quad * 8;
    auto loadB = [&](int kk, int4 (&B)[4]) {        // B[ch*2+nt]
        #pragma unroll
        for (int nt = 0; nt < 2; ++nt) {
            int n = wave * 32 + nt * 16 + col;
            int idx = neigh_s[n * KK + kk];
            if (idx >= 0) {
                const unsigned short* base = xt + (size_t)idx * 64 + pc_b;
                B[nt]     = *(const int4*)(base);
                B[2 + nt] = *(const int4*)(base + 32);
            } else {
                B[nt]     = make_int4(0, 0, 0, 0);
                B[2 + nt] = make_int4(0, 0, 0, 0);
            }
        }
    };

    auto mfma_phase = [&](const unsigned short* wbuf, int4 (&B)[4]) {
        #pragma unroll
        for (int ch = 0; ch < 2; ++ch) {
            const int pc = (ch * 4 + quad) ^ (col & 7);   // XOR-swizzled physical chunk
            #pragma unroll
            for (int mt = 0; mt < 8; ++mt) {
                s8v a = *(const s8v*)&wbuf[(mt * 16 + col) * 64 + pc * 8];
                acc[mt][0] = __builtin_amdgcn_mfma_f32_16x16x32_bf16(a, __builtin_bit_cast(s8v, B[ch * 2 + 0]), acc[mt][0], 0, 0, 0);
                acc[mt][1] = __builtin_amdgcn_mfma_f32_16x16x32_bf16(a, __builtin_bit_cast(s8v, B[ch * 2 + 1]), acc[mt][1], 0, 0, 0);
            }
        }
    };

    int4 B0[4], B1[4];
    loadB(0, B0);

    // 27 = 13*2 + 1; ping-pong (B0,buf0)/(B1,buf1), no register copies
    #pragma unroll 1
    for (int kb = 0; kb < 13; ++kb) {
        int k = kb * 2;
        dmaW(k + 1, 1);
        loadB(k + 1, B1);
        mfma_phase(w_s[0], B0);
        __syncthreads();                 // waves done with buf0; DMA k+1 drained

        if (k + 2 < KK) {
            dmaW(k + 2, 0);
            loadB(k + 2, B0);
        }
        mfma_phase(w_s[1], B1);
        __syncthreads();                 // waves done with buf1; DMA k+2 drained
    }
    mfma_phase(w_s[0], B0);              // k = 26

    // ---- epilogue: D row = quad*4+r (o), col (h); relu + fp32 store ----
    #pragma unroll
    for (int mt = 0; mt < 8; ++mt) {
        #pragma unroll
        for (int nt = 0; nt < 2; ++nt) {
            int hg = hbase + wave * 32 + nt * 16 + col;
            if (hg < HH) {
                #pragma unroll
                for (int r = 0; r < 4; ++r) {
                    int o = mt * 16 + quad * 4 + r;
                    float v = acc[mt][nt][r];
                    out[(size_t)o * HH + hg] = v > 0.f ? v : 0.f;
                }
            }
        }
    }
}

extern "C" void kernel_launch(void* const* d_in, const int* in_sizes, int n_in,
                              void* d_out, int out_size, void* d_ws, size_t ws_size,
                              hipStream_t stream) {
    const float* data_in = (const float*)d_in[0];
    const int*   neigh   = (const int*)d_in[1];
    const float* weight  = (const float*)d_in[2];
    float* out = (float*)d_out;

    unsigned short* xt = (unsigned short*)d_ws;            // H*64 bf16 = 12.8 MB
    unsigned short* wk = xt + (size_t)HH * 64;             // 27*128*64 bf16 = 442 KB

    prep_kernel<<<TB + WB, 256, 0, stream>>>(data_in, weight, xt, wk);
    conv_main<<<NBLK, 256, 0, stream>>>(xt, wk, neigh, out);
}